// Round 1
// baseline (1604.397 us; speedup 1.0000x reference)
//
#include <hip/hip_runtime.h>

typedef __attribute__((ext_vector_type(8))) __bf16 bf16x8;
typedef __attribute__((ext_vector_type(4))) float f32x4;
typedef unsigned short u16;
typedef unsigned int u32;

// ---- LDS layout (bytes) ----
// xs : [80][384] bf16 stride 768   (window input, rows 72..79 zero)
// ow : [80][384] bf16 stride 768   (attention output, per-head slices)
// qh : [80][64]  bf16 stride 128   (q of current head)   \ overlaid by
// kh : [80][64]  bf16 stride 128   (k of current head)   / P [80][128] stride 256
// vt : [64][128] bf16 stride 256   (V^T: row=channel, col=token; cols>=80 zero)
// tab: cos/sin tables [18][16] f32
#define XS_OFF   0
#define OW_OFF   61440
#define QH_OFF   122880
#define KH_OFF   133120
#define P_OFF    122880
#define VT_OFF   143360
#define TC_OFF   159744
#define TS_OFF   160896
#define SMEM_BYTES 162048

__device__ __forceinline__ u16 f2bf(float x){
  u32 u = __float_as_uint(x);
  return (u16)((u + 0x7fffu + ((u >> 16) & 1u)) >> 16);
}

union FragU { uint4 u4; bf16x8 bf; };

// swizzled 16B fragment read: row-major [rows][*] with strideB % 128 == 0
__device__ __forceinline__ bf16x8 lds_frag(const unsigned char* smem, int off, int row, int strideB, int kElem){
  int byte = (row * strideB + kElem * 2) ^ ((row & 7) << 4);
  FragU f;
  f.u4 = *reinterpret_cast<const uint4*>(smem + off + byte);
  return f.bf;
}

__device__ __forceinline__ void lds_store_b16(unsigned char* smem, int off, int row, int strideB, int col, u16 v){
  int byte = (row * strideB + col * 2) ^ ((row & 7) << 4);
  *reinterpret_cast<u16*>(smem + off + byte) = v;
}

__global__ void prep_weights(const float* __restrict__ wq, const float* __restrict__ wp,
                             u16* __restrict__ wqb, u16* __restrict__ wpb){
  int i = blockIdx.x * 256 + threadIdx.x;
  wqb[i] = f2bf(wq[i]);              // grid sized exactly for 442368
  if (i < 147456) wpb[i] = f2bf(wp[i]);
}

__launch_bounds__(384, 1)
__global__ void fused_swin(const float* __restrict__ x,
                           const float* __restrict__ bq,
                           const float* __restrict__ bp,
                           const u16* __restrict__ wq,
                           const u16* __restrict__ wp,
                           float* __restrict__ out)
{
  __shared__ __align__(16) unsigned char smem[SMEM_BYTES];

  const int tid  = threadIdx.x;
  const int wave = tid >> 6;
  const int lane = tid & 63;
  const int l15  = lane & 15;
  const int lhi  = lane >> 4;

  const int wgid = blockIdx.x;       // 0..2047  = b*1024 + wi*32 + wj
  const int bIdx = wgid >> 10;
  const int win  = wgid & 1023;
  const int wi   = win >> 5;
  const int wj   = win & 31;
  const bool maskWin = (wi == 31);   // only bottom row band has a nontrivial mask

  float* tabc = reinterpret_cast<float*>(smem + TC_OFF);
  float* tabs = reinterpret_cast<float*>(smem + TS_OFF);

  // ---- phase 0a: RoPE tables. pos 0..5 = row angle, 6..17 = col angle ----
  if (tid < 288){
    int pos = tid >> 4, m = tid & 15;
    float pv = (pos < 6) ? (float)pos : (float)(pos - 6);
    float ang = pv * __expf(-(float)m * 0.5756462732485114f); // 10000^(-m/16)
    tabc[tid] = cosf(ang);
    tabs[tid] = sinf(ang);
  }

  // ---- phase 0b: zero V^T region (cols >= 80 must be 0 for PV K-padding) ----
  for (int i = tid; i < 4096; i += 384)
    reinterpret_cast<u32*>(smem + VT_OFF)[i] = 0u;

  // ---- phase 0c: gather rolled window into xs (bf16, swizzled) ----
  for (int cid = tid; cid < 3840; cid += 384){    // 80 rows x 48 chunks of 8
    int row = cid / 48;
    int cp  = cid - row * 48;
    u32 pkx = 0, pky = 0, pkz = 0, pkw = 0;
    if (row < 72){
      int r = row / 12, cl = row - r * 12;
      int hh  = wi * 6 + r + 3;   if (hh  >= 192) hh  -= 192;
      int ww2 = wj * 12 + cl + 6; if (ww2 >= 384) ww2 -= 384;
      const float* src = x + (((size_t)bIdx * 192 + hh) * 384 + ww2) * 384 + cp * 8;
      float4 f0 = *reinterpret_cast<const float4*>(src);
      float4 f1 = *reinterpret_cast<const float4*>(src + 4);
      pkx = (u32)f2bf(f0.x) | ((u32)f2bf(f0.y) << 16);
      pky = (u32)f2bf(f0.z) | ((u32)f2bf(f0.w) << 16);
      pkz = (u32)f2bf(f1.x) | ((u32)f2bf(f1.y) << 16);
      pkw = (u32)f2bf(f1.z) | ((u32)f2bf(f1.w) << 16);
    }
    int byte = (row * 768 + cp * 16) ^ ((row & 7) << 4);
    uint4 pk; pk.x = pkx; pk.y = pky; pk.z = pkz; pk.w = pkw;
    *reinterpret_cast<uint4*>(smem + XS_OFF + byte) = pk;
  }
  __syncthreads();

  float sv[5][4];                       // save_attn accumulator (waves 0..4)
  #pragma unroll
  for (int a = 0; a < 5; a++)
    #pragma unroll
    for (int b = 0; b < 4; b++) sv[a][b] = 0.0f;

  f32x4 pfrag[5];                       // softmax probs, carried across barrier

  for (int h = 0; h < 6; ++h){
    // ================= QKV GEMM (M=80, N=192 for this head, K=384) =================
    // wave w owns 2 N-tiles: waves 0,1 -> q; 2,3 -> k; 4,5 -> v
    {
      const int nt0 = wave * 2;
      const int sec = nt0 >> 2;                       // 0=q 1=k 2=v
      const int j0  = sec * 384 + h * 64 + (nt0 & 3) * 16;
      f32x4 acc[5][2];
      #pragma unroll
      for (int mt = 0; mt < 5; mt++){ acc[mt][0] = 0.0f; acc[mt][1] = 0.0f; }
      for (int ks = 0; ks < 12; ++ks){
        const int kEl = ks * 32 + lhi * 8;
        bf16x8 afr[5];
        #pragma unroll
        for (int mt = 0; mt < 5; ++mt)
          afr[mt] = lds_frag(smem, XS_OFF, mt * 16 + l15, 768, kEl);
        bf16x8 bfr[2];
        #pragma unroll
        for (int nt = 0; nt < 2; ++nt){
          FragU f;
          f.u4 = *reinterpret_cast<const uint4*>(wq + (size_t)(j0 + nt * 16 + l15) * 384 + kEl);
          bfr[nt] = f.bf;
        }
        #pragma unroll
        for (int mt = 0; mt < 5; ++mt)
          #pragma unroll
          for (int nt = 0; nt < 2; ++nt)
            acc[mt][nt] = __builtin_amdgcn_mfma_f32_16x16x32_bf16(afr[mt], bfr[nt], acc[mt][nt], 0, 0, 0);
      }
      // bias + RoPE (+ scale on q)
      #pragma unroll
      for (int nt = 0; nt < 2; ++nt){
        const float bias = bq[j0 + nt * 16 + l15];
        const int ch = (nt0 & 3) * 16 + nt * 16 + l15;   // channel within head 0..63
        const int p  = ch >> 1;
        const int m  = p & 15;
        const bool isR = (p < 16);
        const bool ev  = ((ch & 1) == 0);
        #pragma unroll
        for (int mt = 0; mt < 5; ++mt){
          #pragma unroll
          for (int r = 0; r < 4; ++r){
            float v = acc[mt][nt][r] + bias;
            if (sec < 2){
              int t = mt * 16 + lhi * 4 + r; if (t > 71) t = 71;
              int pos = isR ? (t / 12) : (6 + (t % 12));
              float c = tabc[pos * 16 + m];
              float s = tabs[pos * 16 + m];
              float o = __shfl_xor(v, 1);                 // partner channel value
              float nv = ev ? (v * c - o * s) : (o * s + v * c);
              if (sec == 0) nv *= 0.125f;                 // HD^-0.5
              v = nv;
            }
            acc[mt][nt][r] = v;
          }
        }
      }
      // store to LDS: q/k row-major [t][d]; v transposed [d][t]
      if (sec < 2){
        const int offD = (sec == 0) ? QH_OFF : KH_OFF;
        #pragma unroll
        for (int nt = 0; nt < 2; ++nt){
          const int ch = (nt0 & 3) * 16 + nt * 16 + l15;
          #pragma unroll
          for (int mt = 0; mt < 5; ++mt)
            #pragma unroll
            for (int r = 0; r < 4; ++r)
              lds_store_b16(smem, offD, mt * 16 + lhi * 4 + r, 128, ch, f2bf(acc[mt][nt][r]));
        }
      } else {
        #pragma unroll
        for (int nt = 0; nt < 2; ++nt){
          const int ch = (nt0 & 3) * 16 + nt * 16 + l15;
          #pragma unroll
          for (int mt = 0; mt < 5; ++mt){
            int t0 = mt * 16 + lhi * 4;
            uint2 pk;
            pk.x = (u32)f2bf(acc[mt][nt][0]) | ((u32)f2bf(acc[mt][nt][1]) << 16);
            pk.y = (u32)f2bf(acc[mt][nt][2]) | ((u32)f2bf(acc[mt][nt][3]) << 16);
            int byte = (ch * 256 + t0 * 2) ^ ((ch & 7) << 4);
            *reinterpret_cast<uint2*>(smem + VT_OFF + byte) = pk;
          }
        }
      }
    }
    __syncthreads();

    // ================= QK^T + softmax (registers only) =================
    if (wave < 5){
      #pragma unroll
      for (int nt = 0; nt < 5; nt++) pfrag[nt] = 0.0f;
      #pragma unroll
      for (int ks = 0; ks < 2; ++ks){
        const int kEl = ks * 32 + lhi * 8;
        bf16x8 aq = lds_frag(smem, QH_OFF, wave * 16 + l15, 128, kEl);
        #pragma unroll
        for (int nt = 0; nt < 5; ++nt){
          bf16x8 bk = lds_frag(smem, KH_OFF, nt * 16 + l15, 128, kEl);
          pfrag[nt] = __builtin_amdgcn_mfma_f32_16x16x32_bf16(aq, bk, pfrag[nt], 0, 0, 0);
        }
      }
      const int i0 = wave * 16 + lhi * 4;
      float mx[4] = {-1e30f, -1e30f, -1e30f, -1e30f};
      #pragma unroll
      for (int nt = 0; nt < 5; ++nt){
        const int j = nt * 16 + l15;
        #pragma unroll
        for (int r = 0; r < 4; ++r){
          const int i = i0 + r;
          bool valid = (j < 72) && (!maskWin || ((i < 36) == (j < 36)));
          float val = valid ? pfrag[nt][r] : -1e30f;
          pfrag[nt][r] = val;
          mx[r] = fmaxf(mx[r], val);
        }
      }
      #pragma unroll
      for (int d = 1; d < 16; d <<= 1)
        #pragma unroll
        for (int r = 0; r < 4; r++) mx[r] = fmaxf(mx[r], __shfl_xor(mx[r], d));
      float sm[4] = {0, 0, 0, 0};
      #pragma unroll
      for (int nt = 0; nt < 5; nt++)
        #pragma unroll
        for (int r = 0; r < 4; r++){
          float e = __expf(pfrag[nt][r] - mx[r]);
          pfrag[nt][r] = e; sm[r] += e;
        }
      #pragma unroll
      for (int d = 1; d < 16; d <<= 1)
        #pragma unroll
        for (int r = 0; r < 4; r++) sm[r] += __shfl_xor(sm[r], d);
      float inv[4];
      #pragma unroll
      for (int r = 0; r < 4; r++) inv[r] = 1.0f / sm[r];
      #pragma unroll
      for (int nt = 0; nt < 5; nt++)
        #pragma unroll
        for (int r = 0; r < 4; r++){
          float pv2 = pfrag[nt][r] * inv[r];
          pfrag[nt][r] = pv2;
          sv[nt][r] += pv2;                 // head-mean accumulator (regs)
        }
    }
    __syncthreads();   // all q/k reads complete before P overlays them

    if (wave < 5){
      const int i0 = wave * 16 + lhi * 4;
      #pragma unroll
      for (int nt = 0; nt < 5; nt++)
        #pragma unroll
        for (int r = 0; r < 4; r++)
          lds_store_b16(smem, P_OFF, i0 + r, 256, nt * 16 + l15, f2bf(pfrag[nt][r]));
      #pragma unroll
      for (int r = 0; r < 4; r++)          // zero K-pad cols 80..95
        lds_store_b16(smem, P_OFF, i0 + r, 256, 80 + l15, (u16)0);
    }
    __syncthreads();

    // ================= PV (M=80 tokens, N=64 ch, K=96 padded) =================
    if (wave < 5){
      f32x4 oacc[4];
      #pragma unroll
      for (int nt = 0; nt < 4; nt++) oacc[nt] = 0.0f;
      #pragma unroll
      for (int ks = 0; ks < 3; ++ks){
        const int kEl = ks * 32 + lhi * 8;
        bf16x8 ap = lds_frag(smem, P_OFF, wave * 16 + l15, 256, kEl);
        #pragma unroll
        for (int nt = 0; nt < 4; ++nt){
          bf16x8 bv = lds_frag(smem, VT_OFF, nt * 16 + l15, 256, kEl);
          oacc[nt] = __builtin_amdgcn_mfma_f32_16x16x32_bf16(ap, bv, oacc[nt], 0, 0, 0);
        }
      }
      #pragma unroll
      for (int nt = 0; nt < 4; nt++)
        #pragma unroll
        for (int r = 0; r < 4; r++)
          lds_store_b16(smem, OW_OFF, wave * 16 + lhi * 4 + r, 768,
                        h * 64 + nt * 16 + l15, f2bf(oacc[nt][r]));
    }
    __syncthreads();
  } // heads

  // ================= save_attn = mean over heads =================
  if (wave < 5){
    float* so = out + 56623104ull + (size_t)wgid * 5184;
    #pragma unroll
    for (int nt = 0; nt < 5; ++nt){
      const int j = nt * 16 + l15;
      if (j < 72){
        #pragma unroll
        for (int r = 0; r < 4; ++r){
          const int i = wave * 16 + lhi * 4 + r;
          if (i < 72) so[i * 72 + j] = sv[nt][r] * (1.0f / 6.0f);
        }
      }
    }
  }

  // ================= output projection (M=80, N=384, K=384) =================
  {
    f32x4 pacc[5][4];
    #pragma unroll
    for (int mt = 0; mt < 5; mt++)
      #pragma unroll
      for (int nt = 0; nt < 4; nt++) pacc[mt][nt] = 0.0f;
    const int o0 = wave * 64;
    for (int ks = 0; ks < 12; ++ks){
      const int kEl = ks * 32 + lhi * 8;
      bf16x8 afr[5];
      #pragma unroll
      for (int mt = 0; mt < 5; ++mt)
        afr[mt] = lds_frag(smem, OW_OFF, mt * 16 + l15, 768, kEl);
      bf16x8 bfr[4];
      #pragma unroll
      for (int nt = 0; nt < 4; ++nt){
        FragU f;
        f.u4 = *reinterpret_cast<const uint4*>(wp + (size_t)(o0 + nt * 16 + l15) * 384 + kEl);
        bfr[nt] = f.bf;
      }
      #pragma unroll
      for (int mt = 0; mt < 5; ++mt)
        #pragma unroll
        for (int nt = 0; nt < 4; ++nt)
          pacc[mt][nt] = __builtin_amdgcn_mfma_f32_16x16x32_bf16(afr[mt], bfr[nt], pacc[mt][nt], 0, 0, 0);
    }
    float bias[4];
    #pragma unroll
    for (int nt = 0; nt < 4; nt++) bias[nt] = bp[o0 + nt * 16 + l15];
    #pragma unroll
    for (int mt = 0; mt < 5; ++mt){
      #pragma unroll
      for (int r = 0; r < 4; ++r){
        const int t = mt * 16 + lhi * 4 + r;
        if (t < 72){
          const int rr = t / 12, cl = t - (t / 12) * 12;
          int hh  = wi * 6 + rr + 3;  if (hh  >= 192) hh  -= 192;
          int ww2 = wj * 12 + cl + 6; if (ww2 >= 384) ww2 -= 384;
          float* dst = out + (((size_t)bIdx * 192 + hh) * 384 + ww2) * 384 + o0;
          #pragma unroll
          for (int nt = 0; nt < 4; ++nt)
            dst[nt * 16 + l15] = pacc[mt][nt][r] + bias[nt];
        }
      }
    }
  }
}

extern "C" void kernel_launch(void* const* d_in, const int* in_sizes, int n_in,
                              void* d_out, int out_size, void* d_ws, size_t ws_size,
                              hipStream_t stream)
{
  const float* x  = (const float*)d_in[0];
  const float* wq = (const float*)d_in[1];
  const float* bq = (const float*)d_in[2];
  const float* wp = (const float*)d_in[3];
  const float* bp = (const float*)d_in[4];
  float* out = (float*)d_out;

  u16* wqb = (u16*)d_ws;                              // 442368 bf16
  u16* wpb = (u16*)((char*)d_ws + 442368 * 2);        // 147456 bf16

  prep_weights<<<1728, 256, 0, stream>>>(wq, wp, wqb, wpb);
  fused_swin<<<2048, 384, 0, stream>>>(x, bq, bp, wqb, wpb, out);
}